// Round 9
// baseline (101.279 us; speedup 1.0000x reference)
//
#include <hip/hip_runtime.h>

#define NB 32
#define NL 1024
#define NC 64
#define NO 64
constexpr float BN_EPS = 1e-5f;

// ws layout (float units):
//  [0..63]        scale
//  [64..127]      shift
//  [128..32895]   d  (B*L row degrees)
//  [32896..49279] bn partials (128 blocks x 64 ch, sum then sumsq)
//  [131072..]     Yt tiled bf16: [b][kt] 8KB tiles, swizzled   (4 MB)
//  [2097152..]    Abf tiled bf16: [b][mt][kt] 16KB tiles, swizzled (64 MB)
#define SCALE_OFF 0
#define SHIFT_OFF 64
#define D_OFF 128
#define PART_OFF 32896
#define YT_OFF 131072      // byte 512 KB (8KB aligned)
#define ABF_OFF 2097152    // byte 8 MB  (16KB aligned)

typedef short          s16x8 __attribute__((ext_vector_type(8)));
typedef unsigned short u16x8 __attribute__((ext_vector_type(8)));
typedef unsigned short u16x4 __attribute__((ext_vector_type(4)));
typedef float          f32x16 __attribute__((ext_vector_type(16)));
typedef float          f32x4  __attribute__((ext_vector_type(4)));

__device__ inline unsigned short f2bf(float f) {
    union { float f; unsigned u; } v; v.f = f;
    unsigned u = v.u + 0x7FFFu + ((v.u >> 16) & 1u);   // round-to-nearest-even
    return (unsigned short)(u >> 16);
}

__device__ inline void gload16(const void* g, void* l) {
    __builtin_amdgcn_global_load_lds(
        (const __attribute__((address_space(1))) unsigned int*)g,
        (__attribute__((address_space(3))) unsigned int*)l, 16, 0, 0);
}

// ---- Kernel 1: fused  (blocks 0..1023: A degrees + bf16 tile convert, 32 rows/blk)
//                (blocks 1024..1151: BN partial sums over H) -------------------
// Plain (cache-allocating) loads: cross-replay L3 residue on A is worth ~65MB.
// Two half-passes: 16 float4 staged in registers, then convert + 16B stores.
__global__ __launch_bounds__(256) void degcvt_bn(
    const float* __restrict__ A, const float* __restrict__ H,
    float* __restrict__ ws, unsigned short* __restrict__ Abf) {
    const int t = threadIdx.x;
    if (blockIdx.x < 1024) {
        const int gr0 = blockIdx.x * 32;      // global node-row base (b*NL + i)
        const int b   = gr0 >> 10;
        const int i0  = gr0 & 1023;
        const int mt  = i0 >> 7;              // 128-row tile index
        const int r0  = i0 & 127;             // row within tile (multiple of 32)
        const int f   = t & 7;                // 8-float slot within a K-tile
        const int rr  = t >> 3;               // 0..31 row within block
        const int r    = r0 + rr;
        const int grow = gr0 + rr;
        const f32x4* Arow = (const f32x4*)(A + (size_t)grow * NL);
        char* tbase = (char*)Abf + (size_t)(b * 8 + mt) * 16 * 16384;
        const int woff = (r * 128 + f * 16) ^ ((r & 7) << 4);

        float dsum = 0.f;
#pragma unroll
        for (int hp = 0; hp < 2; ++hp) {
            f32x4 va[8], vb[8];
#pragma unroll
            for (int j = 0; j < 8; ++j) {     // phase 1: 16 loads in flight
                va[j] = Arow[(hp * 8 + j) * 16 + f * 2];
                vb[j] = Arow[(hp * 8 + j) * 16 + f * 2 + 1];
            }
            __builtin_amdgcn_sched_barrier(0);
#pragma unroll
            for (int j = 0; j < 8; ++j) {     // phase 2: convert + 16B store
                u16x8 h;
                h[0] = f2bf(va[j].x); h[1] = f2bf(va[j].y);
                h[2] = f2bf(va[j].z); h[3] = f2bf(va[j].w);
                h[4] = f2bf(vb[j].x); h[5] = f2bf(vb[j].y);
                h[6] = f2bf(vb[j].z); h[7] = f2bf(vb[j].w);
                *(u16x8*)(tbase + (hp * 8 + j) * 16384 + woff) = h;
                dsum += va[j].x + va[j].y + va[j].z + va[j].w
                      + vb[j].x + vb[j].y + vb[j].z + vb[j].w;
            }
        }
#pragma unroll
        for (int m = 4; m; m >>= 1) dsum += __shfl_xor(dsum, m, 64);
        if (f == 0) ws[D_OFF + grow] = dsum;
    } else {
        __shared__ float ls[256], ls2[256];
        const int bb = blockIdx.x - 1024;     // 0..127
        const int c = t & 63, rg = t >> 6;    // rg 0..3
        float s = 0.f, s2 = 0.f;
        for (int r = bb * 4 + rg; r < NB * NL; r += 512) {
            float v = H[(size_t)r * NC + c];
            s += v; s2 += v * v;
        }
        ls[t] = s; ls2[t] = s2;
        __syncthreads();
        if (t < 64) {
            float a  = ls[c]  + ls[c + 64]  + ls[c + 128]  + ls[c + 192];
            float a2 = ls2[c] + ls2[c + 64] + ls2[c + 128] + ls2[c + 192];
            ws[PART_OFF + bb * 64 + c] = a;
            ws[PART_OFF + 128 * 64 + bb * 64 + c] = a2;
        }
    }
}

// ---- Kernel 2: finalize BN -> scale/shift ------------------------------------
__global__ void bn_finalize(const float* __restrict__ gamma,
                            const float* __restrict__ beta,
                            float* __restrict__ ws) {
    __shared__ float ls[256], ls2[256];
    int tid = threadIdx.x;
    int c = tid & 63, q = tid >> 6;
    const float* ps  = ws + PART_OFF;
    const float* ps2 = ws + PART_OFF + 128 * 64;
    float s = 0.f, s2 = 0.f;
    for (int p = q * 32; p < q * 32 + 32; ++p) {
        s  += ps[p * 64 + c];
        s2 += ps2[p * 64 + c];
    }
    ls[tid] = s; ls2[tid] = s2;
    __syncthreads();
    if (tid < 64) {
        float t  = ls[c]  + ls[c + 64]  + ls[c + 128]  + ls[c + 192];
        float t2 = ls2[c] + ls2[c + 64] + ls2[c + 128] + ls2[c + 192];
        const float n = (float)(NB * NL);
        float mean = t / n;
        float var  = t2 / n - mean * mean;
        float sc = gamma[c] * rsqrtf(var + BN_EPS);
        ws[SCALE_OFF + c] = sc;
        ws[SHIFT_OFF + c] = beta[c] - mean * sc;
    }
}

// ---- Kernel 3: X = Hn@W + b -> d_out;  Yt tiles = bf16(rsqrt(d)*X) swizzled --
__global__ __launch_bounds__(256) void linear_xy(
    const float* __restrict__ H, const float* __restrict__ Wm,
    const float* __restrict__ bias, const float* __restrict__ ws,
    float* __restrict__ X, unsigned short* __restrict__ Yt) {
    __shared__ float Wl[NC * NO];
    __shared__ float hnbuf[4][NC];
    __shared__ unsigned short ytile[64][66];
    const int b = blockIdx.x >> 4, ch = blockIdx.x & 15;   // ch = K-tile index
    const int r0g = b * NL + ch * 64;
    const int t = threadIdx.x, lane = t & 63, w = t >> 6;
    for (int k = t; k < NC * NO; k += 256) Wl[k] = Wm[k];
    const float sc = ws[SCALE_OFF + lane];
    const float sh = ws[SHIFT_OFF + lane];
    const float bo = bias[lane];
    const float* dbuf = ws + D_OFF;
    __syncthreads();
    for (int rr = w; rr < 64; rr += 4) {
        const int row = r0g + rr;
        float h = H[(size_t)row * NC + lane];
        hnbuf[w][lane] = h * sc + sh;
        float x = bo;
#pragma unroll
        for (int c4 = 0; c4 < NC; c4 += 4) {
            float4 h4 = *(const float4*)(&hnbuf[w][c4]);
            x += h4.x * Wl[(c4 + 0) * NO + lane];
            x += h4.y * Wl[(c4 + 1) * NO + lane];
            x += h4.z * Wl[(c4 + 2) * NO + lane];
            x += h4.w * Wl[(c4 + 3) * NO + lane];
        }
        X[(size_t)row * NO + lane] = x;
        ytile[rr][lane] = f2bf(x * rsqrtf(dbuf[row]));
    }
    __syncthreads();
    // tiled swizzled write: tile (b,ch), element (col, kk=lane)
    char* ybase = (char*)Yt + (size_t)(b * 16 + ch) * 8192;
#pragma unroll
    for (int i2 = 0; i2 < 16; ++i2) {
        const int col = i2 * 4 + w;
        *(unsigned short*)(ybase + ((col * 128 + lane * 2) ^ ((col & 7) << 4))) =
            ytile[lane][col];
    }
}

// ---- Kernel 4: out = leaky(X - sqrt(d_i) * (A @ Y))  [MFMA, gload_lds] -------
__global__ __launch_bounds__(512) void prop_mfma(
    const unsigned short* __restrict__ Abf, const unsigned short* __restrict__ Yt,
    const float* __restrict__ dbuf, float* __restrict__ XO) {

    __shared__ unsigned short Abuf[2][128 * 64];   // 2 x 16 KB (swizzled layout)
    __shared__ unsigned short Ybuf[2][64 * 64];    // 2 x 8 KB
    __shared__ float sdl[128];

    const int b  = blockIdx.x >> 3;
    const int mt = blockIdx.x & 7;
    const int i0 = mt * 128;
    const char* AbT = (const char*)Abf + (size_t)blockIdx.x * 16 * 16384;
    const char* YbT = (const char*)Yt  + (size_t)b * 16 * 8192;

    const int t    = threadIdx.x;
    const int lane = t & 63;
    const int w    = t >> 6;

    if (t < 128) sdl[t] = sqrtf(dbuf[b * NL + i0 + t]);

    const int wr0  = (w >> 1) * 32;
    const int wc0  = (w & 1) * 32;
    const int frow = wr0 + (lane & 31);
    const int fcol = wc0 + (lane & 31);
    const int khb  = (lane >> 5) * 16;

    f32x16 acc;
#pragma unroll
    for (int r = 0; r < 16; ++r) acc[r] = 0.f;

#define STAGE(bi, kt) do {                                                     \
        const char* asrc = AbT + (size_t)(kt) * 16384;                         \
        char* adst = (char*)Abuf[bi];                                          \
        gload16(asrc + w * 2048 + lane * 16,        adst + w * 2048 + lane * 16); \
        gload16(asrc + w * 2048 + 1024 + lane * 16, adst + w * 2048 + 1024 + lane * 16); \
        const char* ysrc = YbT + (size_t)(kt) * 8192;                          \
        gload16(ysrc + w * 1024 + lane * 16, (char*)Ybuf[bi] + w * 1024 + lane * 16); \
    } while (0)

    STAGE(0, 0);
    __syncthreads();

#pragma unroll 1
    for (int kti = 0; kti < 16; ++kti) {
        const int nxt = kti + 1;
        if (nxt < 16) STAGE(nxt & 1, nxt);      // prefetch next tile (async)
        const char* ab  = (const char*)Abuf[kti & 1];
        const char* yb2 = (const char*)Ybuf[kti & 1];
#pragma unroll
        for (int ks = 0; ks < 4; ++ks) {
            const int kb = ks * 32 + khb;
            s16x8 af = *(const s16x8*)(ab  + ((frow * 128 + kb) ^ ((frow & 7) << 4)));
            s16x8 bf = *(const s16x8*)(yb2 + ((fcol * 128 + kb) ^ ((fcol & 7) << 4)));
            acc = __builtin_amdgcn_mfma_f32_32x32x16_bf16(af, bf, acc, 0, 0, 0);
        }
        __syncthreads();                        // drains vmcnt: next tile resident
    }
#undef STAGE

    // epilogue: out = leaky(X - sqrt(d_i) * acc)
#pragma unroll
    for (int reg = 0; reg < 16; ++reg) {
        int row = (reg & 3) + 8 * (reg >> 2) + 4 * (lane >> 5);
        int i   = i0 + wr0 + row;
        int col = wc0 + (lane & 31);
        size_t idx = ((size_t)(b * NL + i)) * NO + col;
        float x = XO[idx];
        float v = x - sdl[wr0 + row] * acc[reg];
        XO[idx] = v > 0.f ? v : 0.01f * v;
    }
}

extern "C" void kernel_launch(void* const* d_in, const int* in_sizes, int n_in,
                              void* d_out, int out_size, void* d_ws, size_t ws_size,
                              hipStream_t stream) {
    const float* H     = (const float*)d_in[0];
    const float* A     = (const float*)d_in[1];
    const float* gamma = (const float*)d_in[2];
    const float* beta  = (const float*)d_in[3];
    const float* Wm    = (const float*)d_in[4];
    const float* bias  = (const float*)d_in[5];
    float* out = (float*)d_out;
    float* ws  = (float*)d_ws;
    unsigned short* Yt  = (unsigned short*)(ws + YT_OFF);
    unsigned short* Abf = (unsigned short*)(ws + ABF_OFF);

    degcvt_bn<<<1152, 256, 0, stream>>>(A, H, ws, Abf);
    bn_finalize<<<1, 256, 0, stream>>>(gamma, beta, ws);
    linear_xy<<<512, 256, 0, stream>>>(H, Wm, bias, ws, out, Yt);
    prop_mfma<<<256, 512, 0, stream>>>(Abf, Yt, ws + D_OFF, out);
}

// Round 10
// 89.683 us; speedup vs baseline: 1.1293x; 1.1293x over previous
//
#include <hip/hip_runtime.h>

#define NB 32
#define NL 1024
#define NC 64
#define NO 64
constexpr float BN_EPS = 1e-5f;

// ws layout (float units):
//  [0..63]        scale
//  [64..127]      shift
//  [128..32895]   d  (B*L row degrees)
//  [32896..49279] bn partials (128 blocks x 64 ch, sum then sumsq)
//  [131072..]     Yt tiled bf16: [b][kt] 8KB tiles, swizzled   (4 MB)
//  [2097152..]    Abf bf16 ROW-MAJOR [b][row][col] (64 MB, no swizzle)
#define SCALE_OFF 0
#define SHIFT_OFF 64
#define D_OFF 128
#define PART_OFF 32896
#define YT_OFF 131072      // byte 512 KB
#define ABF_OFF 2097152    // byte 8 MB

typedef short          s16x8 __attribute__((ext_vector_type(8)));
typedef unsigned short u16x8 __attribute__((ext_vector_type(8)));
typedef float          f32x16 __attribute__((ext_vector_type(16)));
typedef float          f32x4  __attribute__((ext_vector_type(4)));

__device__ inline unsigned short f2bf(float f) {
    union { float f; unsigned u; } v; v.f = f;
    unsigned u = v.u + 0x7FFFu + ((v.u >> 16) & 1u);   // round-to-nearest-even
    return (unsigned short)(u >> 16);
}

__device__ inline void gload16(const void* g, void* l) {
    __builtin_amdgcn_global_load_lds(
        (const __attribute__((address_space(1))) unsigned int*)g,
        (__attribute__((address_space(3))) unsigned int*)l, 16, 0, 0);
}

// ---- Kernel 1: fused  (blocks 0..1023: A degrees + bf16 convert, LINEAR stream)
//                (blocks 1024..1151: BN partial sums over H) -------------------
// A-part: thread t iter s: 32B fp32 load -> 16B bf16 store, both perfectly
// contiguous per wave (1KB wave stores). Degrees via 64-lane shfl + LDS slots.
__global__ __launch_bounds__(256) void degcvt_bn(
    const float* __restrict__ A, const float* __restrict__ H,
    float* __restrict__ ws, unsigned short* __restrict__ Abf) {
    const int t = threadIdx.x;
    if (blockIdx.x < 1024) {
        __shared__ float part[32][2];
        const int wv = t >> 6, lane = t & 63;
        const char* src = (const char*)A   + (size_t)blockIdx.x * 131072 + t * 32;
        char*       dst = (char*)Abf       + (size_t)blockIdx.x * 65536  + t * 16;
#pragma unroll 4
        for (int s = 0; s < 16; ++s) {
            f32x4 a  = *(const f32x4*)(src + s * 8192);
            f32x4 b2 = *(const f32x4*)(src + s * 8192 + 16);
            u16x8 h;
            h[0] = f2bf(a.x);  h[1] = f2bf(a.y);  h[2] = f2bf(a.z);  h[3] = f2bf(a.w);
            h[4] = f2bf(b2.x); h[5] = f2bf(b2.y); h[6] = f2bf(b2.z); h[7] = f2bf(b2.w);
            *(u16x8*)(dst + s * 4096) = h;
            float ps = a.x + a.y + a.z + a.w + b2.x + b2.y + b2.z + b2.w;
#pragma unroll
            for (int m = 32; m; m >>= 1) ps += __shfl_xor(ps, m, 64);
            if (lane == 0) part[2 * s + (wv >> 1)][wv & 1] = ps;  // unique slot/wave
        }
        __syncthreads();
        if (t < 32)
            ws[D_OFF + blockIdx.x * 32 + t] = part[t][0] + part[t][1];
    } else {
        __shared__ float ls[256], ls2[256];
        const int bb = blockIdx.x - 1024;     // 0..127
        const int c = t & 63, rg = t >> 6;    // rg 0..3
        float s = 0.f, s2 = 0.f;
        for (int r = bb * 4 + rg; r < NB * NL; r += 512) {
            float v = H[(size_t)r * NC + c];
            s += v; s2 += v * v;
        }
        ls[t] = s; ls2[t] = s2;
        __syncthreads();
        if (t < 64) {
            float a  = ls[c]  + ls[c + 64]  + ls[c + 128]  + ls[c + 192];
            float a2 = ls2[c] + ls2[c + 64] + ls2[c + 128] + ls2[c + 192];
            ws[PART_OFF + bb * 64 + c] = a;
            ws[PART_OFF + 128 * 64 + bb * 64 + c] = a2;
        }
    }
}

// ---- Kernel 2: finalize BN -> scale/shift ------------------------------------
__global__ void bn_finalize(const float* __restrict__ gamma,
                            const float* __restrict__ beta,
                            float* __restrict__ ws) {
    __shared__ float ls[256], ls2[256];
    int tid = threadIdx.x;
    int c = tid & 63, q = tid >> 6;
    const float* ps  = ws + PART_OFF;
    const float* ps2 = ws + PART_OFF + 128 * 64;
    float s = 0.f, s2 = 0.f;
    for (int p = q * 32; p < q * 32 + 32; ++p) {
        s  += ps[p * 64 + c];
        s2 += ps2[p * 64 + c];
    }
    ls[tid] = s; ls2[tid] = s2;
    __syncthreads();
    if (tid < 64) {
        float t  = ls[c]  + ls[c + 64]  + ls[c + 128]  + ls[c + 192];
        float t2 = ls2[c] + ls2[c + 64] + ls2[c + 128] + ls2[c + 192];
        const float n = (float)(NB * NL);
        float mean = t / n;
        float var  = t2 / n - mean * mean;
        float sc = gamma[c] * rsqrtf(var + BN_EPS);
        ws[SCALE_OFF + c] = sc;
        ws[SHIFT_OFF + c] = beta[c] - mean * sc;
    }
}

// ---- Kernel 3: X = Hn@W + b -> d_out;  Yt tiles = bf16(rsqrt(d)*X) swizzled --
__global__ __launch_bounds__(256) void linear_xy(
    const float* __restrict__ H, const float* __restrict__ Wm,
    const float* __restrict__ bias, const float* __restrict__ ws,
    float* __restrict__ X, unsigned short* __restrict__ Yt) {
    __shared__ float Wl[NC * NO];
    __shared__ float hnbuf[4][NC];
    __shared__ unsigned short ytile[64][66];
    const int b = blockIdx.x >> 4, ch = blockIdx.x & 15;   // ch = K-tile index
    const int r0g = b * NL + ch * 64;
    const int t = threadIdx.x, lane = t & 63, w = t >> 6;
    for (int k = t; k < NC * NO; k += 256) Wl[k] = Wm[k];
    const float sc = ws[SCALE_OFF + lane];
    const float sh = ws[SHIFT_OFF + lane];
    const float bo = bias[lane];
    const float* dbuf = ws + D_OFF;
    __syncthreads();
    for (int rr = w; rr < 64; rr += 4) {
        const int row = r0g + rr;
        float h = H[(size_t)row * NC + lane];
        hnbuf[w][lane] = h * sc + sh;
        float x = bo;
#pragma unroll
        for (int c4 = 0; c4 < NC; c4 += 4) {
            float4 h4 = *(const float4*)(&hnbuf[w][c4]);
            x += h4.x * Wl[(c4 + 0) * NO + lane];
            x += h4.y * Wl[(c4 + 1) * NO + lane];
            x += h4.z * Wl[(c4 + 2) * NO + lane];
            x += h4.w * Wl[(c4 + 3) * NO + lane];
        }
        X[(size_t)row * NO + lane] = x;
        ytile[rr][lane] = f2bf(x * rsqrtf(dbuf[row]));
    }
    __syncthreads();
    // tiled swizzled write: tile (b,ch), element (col, kk=lane)
    char* ybase = (char*)Yt + (size_t)(b * 16 + ch) * 8192;
#pragma unroll
    for (int i2 = 0; i2 < 16; ++i2) {
        const int col = i2 * 4 + w;
        *(unsigned short*)(ybase + ((col * 128 + lane * 2) ^ ((col & 7) << 4))) =
            ytile[lane][col];
    }
}

// ---- Kernel 4: out = leaky(X - sqrt(d_i) * (A @ Y))  [MFMA, gload_lds] -------
// Abf is row-major; the st-swizzle is applied on the per-lane GLOBAL source
// address (rule 21), LDS dest linear, read side identical to before.
__global__ __launch_bounds__(512) void prop_mfma(
    const unsigned short* __restrict__ Abf, const unsigned short* __restrict__ Yt,
    const float* __restrict__ dbuf, float* __restrict__ XO) {

    __shared__ unsigned short Abuf[2][128 * 64];   // 2 x 16 KB (swizzled content)
    __shared__ unsigned short Ybuf[2][64 * 64];    // 2 x 8 KB
    __shared__ float sdl[128];

    const int b  = blockIdx.x >> 3;
    const int mt = blockIdx.x & 7;
    const int i0 = mt * 128;
    const char* YbT = (const char*)Yt + (size_t)b * 16 * 8192;

    const int t    = threadIdx.x;
    const int lane = t & 63;
    const int w    = t >> 6;

    if (t < 128) sdl[t] = sqrtf(dbuf[b * NL + i0 + t]);

    // per-thread constant A source pointers (row-major + inverse swizzle)
    const int L0  = w * 2048 + lane * 16;          // LDS byte offset 0..16383
    const int L1  = L0 + 1024;
    const int ar0 = L0 >> 7, ar1 = L1 >> 7;        // tile row 0..127
    const char* Asrc0 = (const char*)Abf
        + ((size_t)(b * NL + i0 + ar0)) * 2048 + ((L0 & 127) ^ ((ar0 & 7) << 4));
    const char* Asrc1 = (const char*)Abf
        + ((size_t)(b * NL + i0 + ar1)) * 2048 + ((L1 & 127) ^ ((ar1 & 7) << 4));

    const int wr0  = (w >> 1) * 32;
    const int wc0  = (w & 1) * 32;
    const int frow = wr0 + (lane & 31);
    const int fcol = wc0 + (lane & 31);
    const int khb  = (lane >> 5) * 16;

    f32x16 acc;
#pragma unroll
    for (int r = 0; r < 16; ++r) acc[r] = 0.f;

#define STAGE(bi, kt) do {                                                     \
        char* adst = (char*)Abuf[bi];                                          \
        gload16(Asrc0 + (size_t)(kt) * 128, adst + L0);                        \
        gload16(Asrc1 + (size_t)(kt) * 128, adst + L1);                        \
        const char* ysrc = YbT + (size_t)(kt) * 8192;                          \
        gload16(ysrc + w * 1024 + lane * 16, (char*)Ybuf[bi] + w * 1024 + lane * 16); \
    } while (0)

    STAGE(0, 0);
    __syncthreads();

#pragma unroll 1
    for (int kti = 0; kti < 16; ++kti) {
        const int nxt = kti + 1;
        if (nxt < 16) STAGE(nxt & 1, nxt);      // prefetch next tile (async)
        const char* ab  = (const char*)Abuf[kti & 1];
        const char* yb2 = (const char*)Ybuf[kti & 1];
#pragma unroll
        for (int ks = 0; ks < 4; ++ks) {
            const int kb = ks * 32 + khb;
            s16x8 af = *(const s16x8*)(ab  + ((frow * 128 + kb) ^ ((frow & 7) << 4)));
            s16x8 bf = *(const s16x8*)(yb2 + ((fcol * 128 + kb) ^ ((fcol & 7) << 4)));
            acc = __builtin_amdgcn_mfma_f32_32x32x16_bf16(af, bf, acc, 0, 0, 0);
        }
        __syncthreads();                        // drains vmcnt: next tile resident
    }
#undef STAGE

    // epilogue: out = leaky(X - sqrt(d_i) * acc)
#pragma unroll
    for (int reg = 0; reg < 16; ++reg) {
        int row = (reg & 3) + 8 * (reg >> 2) + 4 * (lane >> 5);
        int i   = i0 + wr0 + row;
        int col = wc0 + (lane & 31);
        size_t idx = ((size_t)(b * NL + i)) * NO + col;
        float x = XO[idx];
        float v = x - sdl[wr0 + row] * acc[reg];
        XO[idx] = v > 0.f ? v : 0.01f * v;
    }
}

extern "C" void kernel_launch(void* const* d_in, const int* in_sizes, int n_in,
                              void* d_out, int out_size, void* d_ws, size_t ws_size,
                              hipStream_t stream) {
    const float* H     = (const float*)d_in[0];
    const float* A     = (const float*)d_in[1];
    const float* gamma = (const float*)d_in[2];
    const float* beta  = (const float*)d_in[3];
    const float* Wm    = (const float*)d_in[4];
    const float* bias  = (const float*)d_in[5];
    float* out = (float*)d_out;
    float* ws  = (float*)d_ws;
    unsigned short* Yt  = (unsigned short*)(ws + YT_OFF);
    unsigned short* Abf = (unsigned short*)(ws + ABF_OFF);

    degcvt_bn<<<1152, 256, 0, stream>>>(A, H, ws, Abf);
    bn_finalize<<<1, 256, 0, stream>>>(gamma, beta, ws);
    linear_xy<<<512, 256, 0, stream>>>(H, Wm, bias, ws, out, Yt);
    prop_mfma<<<256, 512, 0, stream>>>(Abf, Yt, ws + D_OFF, out);
}

// Round 11
// 80.170 us; speedup vs baseline: 1.2633x; 1.1187x over previous
//
#include <hip/hip_runtime.h>

#define NB 32
#define NL 1024
#define NC 64
#define NO 64
constexpr float BN_EPS = 1e-5f;

// ws layout (float units):
//  [0..63]        scale
//  [64..127]      shift
//  [128..32895]   d  (B*L row degrees)
//  [32896..49279] bn partials (128 blocks x 64 ch, sum then sumsq)
//  [131072..]     Yt tiled bf16: [b][kt] 8KB tiles, swizzled   (4 MB)
//  [2097152..]    Abf bf16 ROW-MAJOR [b][row][col] (64 MB, no swizzle)
#define SCALE_OFF 0
#define SHIFT_OFF 64
#define D_OFF 128
#define PART_OFF 32896
#define YT_OFF 131072      // byte 512 KB
#define ABF_OFF 2097152    // byte 8 MB

typedef short          s16x8 __attribute__((ext_vector_type(8)));
typedef unsigned short u16x8 __attribute__((ext_vector_type(8)));
typedef unsigned short u16x4 __attribute__((ext_vector_type(4)));
typedef float          f32x16 __attribute__((ext_vector_type(16)));
typedef float          f32x4  __attribute__((ext_vector_type(4)));

__device__ inline unsigned short f2bf(float f) {
    union { float f; unsigned u; } v; v.f = f;
    unsigned u = v.u + 0x7FFFu + ((v.u >> 16) & 1u);   // round-to-nearest-even
    return (unsigned short)(u >> 16);
}

__device__ inline void gload16(const void* g, void* l) {
    __builtin_amdgcn_global_load_lds(
        (const __attribute__((address_space(1))) unsigned int*)g,
        (__attribute__((address_space(3))) unsigned int*)l, 16, 0, 0);
}

// ---- Kernel 1: fused  (blocks 0..1023: A degrees + bf16 convert via
//                        global_load_lds chunk pipeline, 32 rows/block)
//                (blocks 1024..1151: BN partial sums over H, float4) ----------
__global__ __launch_bounds__(256) void degcvt_bn(
    const float* __restrict__ A, const float* __restrict__ H,
    float* __restrict__ ws, unsigned short* __restrict__ Abf) {
    __shared__ f32x4 smem4[2048];            // 32 KB: 2 x 16KB chunk dbuf / BN part
    const int t = threadIdx.x;
    if (blockIdx.x < 1024) {
        const int lane = t & 63, w = t >> 6;
        const size_t row0 = (size_t)blockIdx.x * 32;           // 32 A-rows/block
        const char* src  = (const char*)A   + row0 * 4096;     // 128 KB in
        char*       dstA = (char*)Abf       + row0 * 2048;     // 64 KB out
        // chunk = 4 rows (16 KB). Wave w stages & consumes row w of each chunk.
        const int lo = w * 4096 + lane * 16;                   // wave-region offset
#define STG(bi, c) do {                                                        \
            char* d0 = (char*)(smem4 + (bi) * 1024) + lo;                      \
            const char* s0 = src + (c) * 16384 + lo;                           \
            gload16(s0,        d0);                                            \
            gload16(s0 + 1024, d0 + 1024);                                     \
            gload16(s0 + 2048, d0 + 2048);                                     \
            gload16(s0 + 3072, d0 + 3072);                                     \
        } while (0)
        STG(0, 0);
        __syncthreads();
#pragma unroll 1
        for (int c = 0; c < 8; ++c) {
            if (c + 1 < 8) STG((c + 1) & 1, c + 1);            // async prefetch
            const char* cb = (const char*)(smem4 + (c & 1) * 1024) + lo;
            float s = 0.f;
            char* orow = dstA + (size_t)(c * 4 + w) * 2048 + lane * 8;
#pragma unroll
            for (int j = 0; j < 4; ++j) {
                f32x4 v = *(const f32x4*)(cb + j * 1024);
                u16x4 h;
                h[0] = f2bf(v.x); h[1] = f2bf(v.y);
                h[2] = f2bf(v.z); h[3] = f2bf(v.w);
                *(u16x4*)(orow + j * 512) = h;
                s += v.x + v.y + v.z + v.w;
            }
#pragma unroll
            for (int m = 32; m; m >>= 1) s += __shfl_xor(s, m, 64);
            if (lane == 0) ws[D_OFF + row0 + c * 4 + w] = s;   // wave owns the row
            __syncthreads();                                   // chunk c+1 resident
        }
#undef STG
    } else {
        // BN stats: block covers 256 rows (4096 float4), fully coalesced.
        const int bb = blockIdx.x - 1024;                      // 0..127
        const float4* Hv = (const float4*)H + bb * 4096;
        float s0 = 0.f, s1 = 0.f, s2 = 0.f, s3 = 0.f;
        float q0 = 0.f, q1 = 0.f, q2 = 0.f, q3 = 0.f;
#pragma unroll 4
        for (int s = 0; s < 16; ++s) {
            float4 v = Hv[s * 256 + t];
            s0 += v.x; q0 += v.x * v.x;
            s1 += v.y; q1 += v.y * v.y;
            s2 += v.z; q2 += v.z * v.z;
            s3 += v.w; q3 += v.w * v.w;
        }
        float* part = (float*)smem4;                           // [256][8]
        part[t * 8 + 0] = s0; part[t * 8 + 1] = s1;
        part[t * 8 + 2] = s2; part[t * 8 + 3] = s3;
        part[t * 8 + 4] = q0; part[t * 8 + 5] = q1;
        part[t * 8 + 6] = q2; part[t * 8 + 7] = q3;
        __syncthreads();
        if (t < 64) {
            const int g = t >> 2, e = t & 3;   // contributors: threads g+16k
            float a = 0.f, a2 = 0.f;
#pragma unroll
            for (int k = 0; k < 16; ++k) {
                a  += part[(g + 16 * k) * 8 + e];
                a2 += part[(g + 16 * k) * 8 + 4 + e];
            }
            ws[PART_OFF + bb * 64 + t] = a;
            ws[PART_OFF + 128 * 64 + bb * 64 + t] = a2;
        }
    }
}

// ---- Kernel 2: finalize BN -> scale/shift ------------------------------------
__global__ void bn_finalize(const float* __restrict__ gamma,
                            const float* __restrict__ beta,
                            float* __restrict__ ws) {
    __shared__ float ls[256], ls2[256];
    int tid = threadIdx.x;
    int c = tid & 63, q = tid >> 6;
    const float* ps  = ws + PART_OFF;
    const float* ps2 = ws + PART_OFF + 128 * 64;
    float s = 0.f, s2 = 0.f;
    for (int p = q * 32; p < q * 32 + 32; ++p) {
        s  += ps[p * 64 + c];
        s2 += ps2[p * 64 + c];
    }
    ls[tid] = s; ls2[tid] = s2;
    __syncthreads();
    if (tid < 64) {
        float t  = ls[c]  + ls[c + 64]  + ls[c + 128]  + ls[c + 192];
        float t2 = ls2[c] + ls2[c + 64] + ls2[c + 128] + ls2[c + 192];
        const float n = (float)(NB * NL);
        float mean = t / n;
        float var  = t2 / n - mean * mean;
        float sc = gamma[c] * rsqrtf(var + BN_EPS);
        ws[SCALE_OFF + c] = sc;
        ws[SHIFT_OFF + c] = beta[c] - mean * sc;
    }
}

// ---- Kernel 3: X = Hn@W + b -> d_out;  Yt tiles = bf16(rsqrt(d)*X) swizzled --
__global__ __launch_bounds__(256) void linear_xy(
    const float* __restrict__ H, const float* __restrict__ Wm,
    const float* __restrict__ bias, const float* __restrict__ ws,
    float* __restrict__ X, unsigned short* __restrict__ Yt) {
    __shared__ float Wl[NC * NO];
    __shared__ float hnbuf[4][NC];
    __shared__ unsigned short ytile[64][66];
    const int b = blockIdx.x >> 4, ch = blockIdx.x & 15;   // ch = K-tile index
    const int r0g = b * NL + ch * 64;
    const int t = threadIdx.x, lane = t & 63, w = t >> 6;
    for (int k = t; k < NC * NO; k += 256) Wl[k] = Wm[k];
    const float sc = ws[SCALE_OFF + lane];
    const float sh = ws[SHIFT_OFF + lane];
    const float bo = bias[lane];
    const float* dbuf = ws + D_OFF;
    __syncthreads();
    for (int rr = w; rr < 64; rr += 4) {
        const int row = r0g + rr;
        float h = H[(size_t)row * NC + lane];
        hnbuf[w][lane] = h * sc + sh;
        float x = bo;
#pragma unroll
        for (int c4 = 0; c4 < NC; c4 += 4) {
            float4 h4 = *(const float4*)(&hnbuf[w][c4]);
            x += h4.x * Wl[(c4 + 0) * NO + lane];
            x += h4.y * Wl[(c4 + 1) * NO + lane];
            x += h4.z * Wl[(c4 + 2) * NO + lane];
            x += h4.w * Wl[(c4 + 3) * NO + lane];
        }
        X[(size_t)row * NO + lane] = x;
        ytile[rr][lane] = f2bf(x * rsqrtf(dbuf[row]));
    }
    __syncthreads();
    // tiled swizzled write: tile (b,ch), element (col, kk=lane)
    char* ybase = (char*)Yt + (size_t)(b * 16 + ch) * 8192;
#pragma unroll
    for (int i2 = 0; i2 < 16; ++i2) {
        const int col = i2 * 4 + w;
        *(unsigned short*)(ybase + ((col * 128 + lane * 2) ^ ((col & 7) << 4))) =
            ytile[lane][col];
    }
}

// ---- Kernel 4: out = leaky(X - sqrt(d_i) * (A @ Y))  [MFMA, gload_lds] -------
// Abf is row-major; the st-swizzle is applied on the per-lane GLOBAL source
// address (rule 21), LDS dest linear, read side identical to before.
__global__ __launch_bounds__(512) void prop_mfma(
    const unsigned short* __restrict__ Abf, const unsigned short* __restrict__ Yt,
    const float* __restrict__ dbuf, float* __restrict__ XO) {

    __shared__ unsigned short Abuf[2][128 * 64];   // 2 x 16 KB (swizzled content)
    __shared__ unsigned short Ybuf[2][64 * 64];    // 2 x 8 KB
    __shared__ float sdl[128];

    const int b  = blockIdx.x >> 3;
    const int mt = blockIdx.x & 7;
    const int i0 = mt * 128;
    const char* YbT = (const char*)Yt + (size_t)b * 16 * 8192;

    const int t    = threadIdx.x;
    const int lane = t & 63;
    const int w    = t >> 6;

    if (t < 128) sdl[t] = sqrtf(dbuf[b * NL + i0 + t]);

    // per-thread constant A source pointers (row-major + inverse swizzle)
    const int L0  = w * 2048 + lane * 16;          // LDS byte offset 0..16383
    const int L1  = L0 + 1024;
    const int ar0 = L0 >> 7, ar1 = L1 >> 7;        // tile row 0..127
    const char* Asrc0 = (const char*)Abf
        + ((size_t)(b * NL + i0 + ar0)) * 2048 + ((L0 & 127) ^ ((ar0 & 7) << 4));
    const char* Asrc1 = (const char*)Abf
        + ((size_t)(b * NL + i0 + ar1)) * 2048 + ((L1 & 127) ^ ((ar1 & 7) << 4));

    const int wr0  = (w >> 1) * 32;
    const int wc0  = (w & 1) * 32;
    const int frow = wr0 + (lane & 31);
    const int fcol = wc0 + (lane & 31);
    const int khb  = (lane >> 5) * 16;

    f32x16 acc;
#pragma unroll
    for (int r = 0; r < 16; ++r) acc[r] = 0.f;

#define STAGE(bi, kt) do {                                                     \
        char* adst = (char*)Abuf[bi];                                          \
        gload16(Asrc0 + (size_t)(kt) * 128, adst + L0);                        \
        gload16(Asrc1 + (size_t)(kt) * 128, adst + L1);                        \
        const char* ysrc = YbT + (size_t)(kt) * 8192;                          \
        gload16(ysrc + w * 1024 + lane * 16, (char*)Ybuf[bi] + w * 1024 + lane * 16); \
    } while (0)

    STAGE(0, 0);
    __syncthreads();

#pragma unroll 1
    for (int kti = 0; kti < 16; ++kti) {
        const int nxt = kti + 1;
        if (nxt < 16) STAGE(nxt & 1, nxt);      // prefetch next tile (async)
        const char* ab  = (const char*)Abuf[kti & 1];
        const char* yb2 = (const char*)Ybuf[kti & 1];
#pragma unroll
        for (int ks = 0; ks < 4; ++ks) {
            const int kb = ks * 32 + khb;
            s16x8 af = *(const s16x8*)(ab  + ((frow * 128 + kb) ^ ((frow & 7) << 4)));
            s16x8 bf = *(const s16x8*)(yb2 + ((fcol * 128 + kb) ^ ((fcol & 7) << 4)));
            acc = __builtin_amdgcn_mfma_f32_32x32x16_bf16(af, bf, acc, 0, 0, 0);
        }
        __syncthreads();                        // drains vmcnt: next tile resident
    }
#undef STAGE

    // epilogue: out = leaky(X - sqrt(d_i) * acc)
#pragma unroll
    for (int reg = 0; reg < 16; ++reg) {
        int row = (reg & 3) + 8 * (reg >> 2) + 4 * (lane >> 5);
        int i   = i0 + wr0 + row;
        int col = wc0 + (lane & 31);
        size_t idx = ((size_t)(b * NL + i)) * NO + col;
        float x = XO[idx];
        float v = x - sdl[wr0 + row] * acc[reg];
        XO[idx] = v > 0.f ? v : 0.01f * v;
    }
}

extern "C" void kernel_launch(void* const* d_in, const int* in_sizes, int n_in,
                              void* d_out, int out_size, void* d_ws, size_t ws_size,
                              hipStream_t stream) {
    const float* H     = (const float*)d_in[0];
    const float* A     = (const float*)d_in[1];
    const float* gamma = (const float*)d_in[2];
    const float* beta  = (const float*)d_in[3];
    const float* Wm    = (const float*)d_in[4];
    const float* bias  = (const float*)d_in[5];
    float* out = (float*)d_out;
    float* ws  = (float*)d_ws;
    unsigned short* Yt  = (unsigned short*)(ws + YT_OFF);
    unsigned short* Abf = (unsigned short*)(ws + ABF_OFF);

    degcvt_bn<<<1152, 256, 0, stream>>>(A, H, ws, Abf);
    bn_finalize<<<1, 256, 0, stream>>>(gamma, beta, ws);
    linear_xy<<<512, 256, 0, stream>>>(H, Wm, bias, ws, out, Yt);
    prop_mfma<<<256, 512, 0, stream>>>(Abf, Yt, ws + D_OFF, out);
}

// Round 12
// 69.939 us; speedup vs baseline: 1.4481x; 1.1463x over previous
//
#include <hip/hip_runtime.h>

#define NB 32
#define NL 1024
#define NC 64
#define NO 64
constexpr float BN_EPS = 1e-5f;

// ws layout (float units):
//  [0..32767+128] d  (B*L row degrees)  at D_OFF
//  [32896..49279] bn partials (128 blocks x 64 ch, sum then sumsq)
//  [131072..]     Yt tiled bf16: [b][kt] 8KB tiles, swizzled   (4 MB)
//  [2097152..]    Abf bf16 ROW-MAJOR [b][row][col] (64 MB, no swizzle)
#define D_OFF 128
#define PART_OFF 32896
#define YT_OFF 131072      // byte 512 KB
#define ABF_OFF 2097152    // byte 8 MB

typedef short          s16x8 __attribute__((ext_vector_type(8)));
typedef unsigned short u16x8 __attribute__((ext_vector_type(8)));
typedef unsigned short u16x4 __attribute__((ext_vector_type(4)));
typedef float          f32x16 __attribute__((ext_vector_type(16)));
typedef float          f32x4  __attribute__((ext_vector_type(4)));

__device__ inline unsigned short f2bf(float f) {
    union { float f; unsigned u; } v; v.f = f;
    unsigned u = v.u + 0x7FFFu + ((v.u >> 16) & 1u);   // round-to-nearest-even
    return (unsigned short)(u >> 16);
}

__device__ inline void gload16(const void* g, void* l) {
    __builtin_amdgcn_global_load_lds(
        (const __attribute__((address_space(1))) unsigned int*)g,
        (__attribute__((address_space(3))) unsigned int*)l, 16, 0, 0);
}

// ---- Kernel 1: fused  (blocks 0..1023: A degrees + bf16 convert via
//                        global_load_lds chunk pipeline, 32 rows/block)
//                (blocks 1024..1151: BN partial sums over H, float4) ----------
__global__ __launch_bounds__(256) void degcvt_bn(
    const float* __restrict__ A, const float* __restrict__ H,
    float* __restrict__ ws, unsigned short* __restrict__ Abf) {
    __shared__ f32x4 smem4[2048];            // 32 KB: 2 x 16KB chunk dbuf / BN part
    const int t = threadIdx.x;
    if (blockIdx.x < 1024) {
        const int lane = t & 63, w = t >> 6;
        const size_t row0 = (size_t)blockIdx.x * 32;           // 32 A-rows/block
        const char* src  = (const char*)A   + row0 * 4096;     // 128 KB in
        char*       dstA = (char*)Abf       + row0 * 2048;     // 64 KB out
        // chunk = 4 rows (16 KB). Wave w stages & consumes row w of each chunk.
        const int lo = w * 4096 + lane * 16;                   // wave-region offset
#define STG(bi, c) do {                                                        \
            char* d0 = (char*)(smem4 + (bi) * 1024) + lo;                      \
            const char* s0 = src + (c) * 16384 + lo;                           \
            gload16(s0,        d0);                                            \
            gload16(s0 + 1024, d0 + 1024);                                     \
            gload16(s0 + 2048, d0 + 2048);                                     \
            gload16(s0 + 3072, d0 + 3072);                                     \
        } while (0)
        STG(0, 0);
        __syncthreads();
#pragma unroll 1
        for (int c = 0; c < 8; ++c) {
            if (c + 1 < 8) STG((c + 1) & 1, c + 1);            // async prefetch
            const char* cb = (const char*)(smem4 + (c & 1) * 1024) + lo;
            float s = 0.f;
            char* orow = dstA + (size_t)(c * 4 + w) * 2048 + lane * 8;
#pragma unroll
            for (int j = 0; j < 4; ++j) {
                f32x4 v = *(const f32x4*)(cb + j * 1024);
                u16x4 h;
                h[0] = f2bf(v.x); h[1] = f2bf(v.y);
                h[2] = f2bf(v.z); h[3] = f2bf(v.w);
                *(u16x4*)(orow + j * 512) = h;
                s += v.x + v.y + v.z + v.w;
            }
#pragma unroll
            for (int m = 32; m; m >>= 1) s += __shfl_xor(s, m, 64);
            if (lane == 0) ws[D_OFF + row0 + c * 4 + w] = s;   // wave owns the row
            __syncthreads();                                   // chunk c+1 resident
        }
#undef STG
    } else {
        // BN stats: block covers 256 rows (4096 float4), fully coalesced.
        const int bb = blockIdx.x - 1024;                      // 0..127
        const float4* Hv = (const float4*)H + bb * 4096;
        float s0 = 0.f, s1 = 0.f, s2 = 0.f, s3 = 0.f;
        float q0 = 0.f, q1 = 0.f, q2 = 0.f, q3 = 0.f;
#pragma unroll 4
        for (int s = 0; s < 16; ++s) {
            float4 v = Hv[s * 256 + t];
            s0 += v.x; q0 += v.x * v.x;
            s1 += v.y; q1 += v.y * v.y;
            s2 += v.z; q2 += v.z * v.z;
            s3 += v.w; q3 += v.w * v.w;
        }
        float* part = (float*)smem4;                           // [256][8]
        part[t * 8 + 0] = s0; part[t * 8 + 1] = s1;
        part[t * 8 + 2] = s2; part[t * 8 + 3] = s3;
        part[t * 8 + 4] = q0; part[t * 8 + 5] = q1;
        part[t * 8 + 6] = q2; part[t * 8 + 7] = q3;
        __syncthreads();
        if (t < 64) {
            const int g = t >> 2, e = t & 3;   // contributors: threads g+16k
            float a = 0.f, a2 = 0.f;
#pragma unroll
            for (int k = 0; k < 16; ++k) {
                a  += part[(g + 16 * k) * 8 + e];
                a2 += part[(g + 16 * k) * 8 + 4 + e];
            }
            ws[PART_OFF + bb * 64 + t] = a;
            ws[PART_OFF + 128 * 64 + bb * 64 + t] = a2;
        }
    }
}

// ---- Kernel 2: X = Hn@W + b -> d_out;  Yt tiles = bf16(rsqrt(d)*X) swizzled --
// BN finalize folded in: every block redundantly reduces the partials (64KB L2).
__global__ __launch_bounds__(256) void linear_xy(
    const float* __restrict__ H, const float* __restrict__ Wm,
    const float* __restrict__ bias, const float* __restrict__ gamma,
    const float* __restrict__ beta, const float* __restrict__ ws,
    float* __restrict__ X, unsigned short* __restrict__ Yt) {
    __shared__ float Wl[NC * NO];
    __shared__ float hnbuf[4][NC];
    __shared__ unsigned short ytile[64][66];
    __shared__ float ls[256], ls2[256];
    __shared__ float sscale[64], sshift[64];
    const int b = blockIdx.x >> 4, ch = blockIdx.x & 15;   // ch = K-tile index
    const int r0g = b * NL + ch * 64;
    const int t = threadIdx.x, lane = t & 63, w = t >> 6;
    // --- inline BN finalize (redundant per block) ---
    {
        const float* ps  = ws + PART_OFF;
        const float* ps2 = ws + PART_OFF + 128 * 64;
        const int c = t & 63, q = t >> 6;
        float s = 0.f, s2 = 0.f;
        for (int p = q * 32; p < q * 32 + 32; ++p) {
            s  += ps[p * 64 + c];
            s2 += ps2[p * 64 + c];
        }
        ls[t] = s; ls2[t] = s2;
        __syncthreads();
        if (t < 64) {
            float T  = ls[c]  + ls[c + 64]  + ls[c + 128]  + ls[c + 192];
            float T2 = ls2[c] + ls2[c + 64] + ls2[c + 128] + ls2[c + 192];
            const float n = (float)(NB * NL);
            float mean = T / n;
            float var  = T2 / n - mean * mean;
            float sc = gamma[c] * rsqrtf(var + BN_EPS);
            sscale[c] = sc;
            sshift[c] = beta[c] - mean * sc;
        }
    }
    for (int k = t; k < NC * NO; k += 256) Wl[k] = Wm[k];
    __syncthreads();
    const float sc = sscale[lane];
    const float sh = sshift[lane];
    const float bo = bias[lane];
    const float* dbuf = ws + D_OFF;
    for (int rr = w; rr < 64; rr += 4) {
        const int row = r0g + rr;
        float h = H[(size_t)row * NC + lane];
        hnbuf[w][lane] = h * sc + sh;
        float x = bo;
#pragma unroll
        for (int c4 = 0; c4 < NC; c4 += 4) {
            float4 h4 = *(const float4*)(&hnbuf[w][c4]);
            x += h4.x * Wl[(c4 + 0) * NO + lane];
            x += h4.y * Wl[(c4 + 1) * NO + lane];
            x += h4.z * Wl[(c4 + 2) * NO + lane];
            x += h4.w * Wl[(c4 + 3) * NO + lane];
        }
        X[(size_t)row * NO + lane] = x;
        ytile[rr][lane] = f2bf(x * rsqrtf(dbuf[row]));
    }
    __syncthreads();
    // tiled swizzled write: tile (b,ch), element (col, kk=lane)
    char* ybase = (char*)Yt + (size_t)(b * 16 + ch) * 8192;
#pragma unroll
    for (int i2 = 0; i2 < 16; ++i2) {
        const int col = i2 * 4 + w;
        *(unsigned short*)(ybase + ((col * 128 + lane * 2) ^ ((col & 7) << 4))) =
            ytile[lane][col];
    }
}

// ---- Kernel 3: out = leaky(X - sqrt(d_i) * (A @ Y))  [MFMA, gload_lds] -------
// 64-row tiles, 512 blocks = 2 blocks/CU: cross-block overlap hides the
// per-K-step vmcnt(0)+barrier drain. 4 waves, each one 32x32 quadrant.
__global__ __launch_bounds__(256) void prop_mfma(
    const unsigned short* __restrict__ Abf, const unsigned short* __restrict__ Yt,
    const float* __restrict__ dbuf, float* __restrict__ XO) {

    __shared__ unsigned short Abuf[2][64 * 64];    // 2 x 8 KB (swizzled content)
    __shared__ unsigned short Ybuf[2][64 * 64];    // 2 x 8 KB
    __shared__ float sdl[64];

    const int b  = blockIdx.x >> 4;
    const int mt = blockIdx.x & 15;
    const int i0 = mt * 64;
    const char* YbT = (const char*)Yt + (size_t)b * 16 * 8192;

    const int t    = threadIdx.x;
    const int lane = t & 63;
    const int w    = t >> 6;

    if (t < 64) sdl[t] = sqrtf(dbuf[b * NL + i0 + t]);

    // staging dest offsets (wave-uniform base + lane*16), cover 8KB in 2 calls
    const int L0  = w * 2048 + lane * 16;          // LDS byte offset 0..8191
    const int L1  = L0 + 1024;
    // A source: row-major Abf + inverse swizzle (rule 21)
    const int ar0 = L0 >> 7, ar1 = L1 >> 7;        // tile row 0..63
    const char* Asrc0 = (const char*)Abf
        + ((size_t)(b * NL + i0 + ar0)) * 2048 + ((L0 & 127) ^ ((ar0 & 7) << 4));
    const char* Asrc1 = (const char*)Abf
        + ((size_t)(b * NL + i0 + ar1)) * 2048 + ((L1 & 127) ^ ((ar1 & 7) << 4));

    const int wr0  = (w >> 1) * 32;
    const int wc0  = (w & 1) * 32;
    const int frow = wr0 + (lane & 31);
    const int fcol = wc0 + (lane & 31);
    const int khb  = (lane >> 5) * 16;

    f32x16 acc;
#pragma unroll
    for (int r = 0; r < 16; ++r) acc[r] = 0.f;

#define STAGE(bi, kt) do {                                                     \
        char* adst = (char*)Abuf[bi];                                          \
        gload16(Asrc0 + (size_t)(kt) * 128, adst + L0);                        \
        gload16(Asrc1 + (size_t)(kt) * 128, adst + L1);                        \
        const char* ysrc = YbT + (size_t)(kt) * 8192;                          \
        char* ydst = (char*)Ybuf[bi];                                          \
        gload16(ysrc + L0, ydst + L0);                                         \
        gload16(ysrc + L1, ydst + L1);                                         \
    } while (0)

    STAGE(0, 0);
    __syncthreads();

#pragma unroll 1
    for (int kti = 0; kti < 16; ++kti) {
        const int nxt = kti + 1;
        if (nxt < 16) STAGE(nxt & 1, nxt);      // prefetch next tile (async)
        const char* ab  = (const char*)Abuf[kti & 1];
        const char* yb2 = (const char*)Ybuf[kti & 1];
#pragma unroll
        for (int ks = 0; ks < 4; ++ks) {
            const int kb = ks * 32 + khb;
            s16x8 af = *(const s16x8*)(ab  + ((frow * 128 + kb) ^ ((frow & 7) << 4)));
            s16x8 bf = *(const s16x8*)(yb2 + ((fcol * 128 + kb) ^ ((fcol & 7) << 4)));
            acc = __builtin_amdgcn_mfma_f32_32x32x16_bf16(af, bf, acc, 0, 0, 0);
        }
        __syncthreads();                        // drains vmcnt: next tile resident
    }
#undef STAGE

    // epilogue: out = leaky(X - sqrt(d_i) * acc)
#pragma unroll
    for (int reg = 0; reg < 16; ++reg) {
        int row = (reg & 3) + 8 * (reg >> 2) + 4 * (lane >> 5);
        int i   = i0 + wr0 + row;
        int col = wc0 + (lane & 31);
        size_t idx = ((size_t)(b * NL + i)) * NO + col;
        float x = XO[idx];
        float v = x - sdl[wr0 + row] * acc[reg];
        XO[idx] = v > 0.f ? v : 0.01f * v;
    }
}

extern "C" void kernel_launch(void* const* d_in, const int* in_sizes, int n_in,
                              void* d_out, int out_size, void* d_ws, size_t ws_size,
                              hipStream_t stream) {
    const float* H     = (const float*)d_in[0];
    const float* A     = (const float*)d_in[1];
    const float* gamma = (const float*)d_in[2];
    const float* beta  = (const float*)d_in[3];
    const float* Wm    = (const float*)d_in[4];
    const float* bias  = (const float*)d_in[5];
    float* out = (float*)d_out;
    float* ws  = (float*)d_ws;
    unsigned short* Yt  = (unsigned short*)(ws + YT_OFF);
    unsigned short* Abf = (unsigned short*)(ws + ABF_OFF);

    degcvt_bn<<<1152, 256, 0, stream>>>(A, H, ws, Abf);
    linear_xy<<<512, 256, 0, stream>>>(H, Wm, bias, gamma, beta, ws, out, Yt);
    prop_mfma<<<512, 256, 0, stream>>>(Abf, Yt, ws + D_OFF, out);
}

// Round 13
// 68.646 us; speedup vs baseline: 1.4754x; 1.0188x over previous
//
#include <hip/hip_runtime.h>

#define NB 32
#define NL 1024
#define NC 64
#define NO 64
constexpr float BN_EPS = 1e-5f;

// ws layout (float units):
//  [128..32895]   d  (B*L row degrees)  at D_OFF
//  [32896..49279] bn partials (128 blocks x 64 ch, sum then sumsq)
//  [131072..]     Yt tiled bf16: [b][kt] 8KB tiles, swizzled   (4 MB)
#define D_OFF 128
#define PART_OFF 32896
#define YT_OFF 131072      // byte 512 KB

typedef short          s16x8 __attribute__((ext_vector_type(8)));
typedef float          f32x16 __attribute__((ext_vector_type(16)));
typedef float          f32x4  __attribute__((ext_vector_type(4)));

__device__ inline unsigned short f2bf(float f) {
    union { float f; unsigned u; } v; v.f = f;
    unsigned u = v.u + 0x7FFFu + ((v.u >> 16) & 1u);   // round-to-nearest-even
    return (unsigned short)(u >> 16);
}

__device__ inline void gload16(const void* g, void* l) {
    __builtin_amdgcn_global_load_lds(
        (const __attribute__((address_space(1))) unsigned int*)g,
        (__attribute__((address_space(3))) unsigned int*)l, 16, 0, 0);
}

// fp32x8 -> bf16x8 via packed cvt (RNE on gfx950)
__device__ inline s16x8 cvt8(f32x4 lo, f32x4 hi) {
    union { unsigned int i[4]; s16x8 v; } u;
    asm("v_cvt_pk_bf16_f32 %0, %1, %2" : "=v"(u.i[0]) : "v"(lo.x), "v"(lo.y));
    asm("v_cvt_pk_bf16_f32 %0, %1, %2" : "=v"(u.i[1]) : "v"(lo.z), "v"(lo.w));
    asm("v_cvt_pk_bf16_f32 %0, %1, %2" : "=v"(u.i[2]) : "v"(hi.x), "v"(hi.y));
    asm("v_cvt_pk_bf16_f32 %0, %1, %2" : "=v"(u.i[3]) : "v"(hi.z), "v"(hi.w));
    return u.v;
}

// ---- Kernel 1: (blocks 0..1023: A row degrees via gload_lds chunk pipeline)
//                (blocks 1024..1151: BN partial sums over H, float4) ----------
__global__ __launch_bounds__(256) void deg_bn(
    const float* __restrict__ A, const float* __restrict__ H,
    float* __restrict__ ws) {
    __shared__ f32x4 smem4[2048];            // 32 KB: 2 x 16KB chunk dbuf / BN part
    const int t = threadIdx.x;
    if (blockIdx.x < 1024) {
        const int lane = t & 63, w = t >> 6;
        const size_t row0 = (size_t)blockIdx.x * 32;           // 32 A-rows/block
        const char* src = (const char*)A + row0 * 4096;        // 128 KB in
        const int lo = w * 4096 + lane * 16;                   // wave-region offset
#define STG(bi, c) do {                                                        \
            char* d0 = (char*)(smem4 + (bi) * 1024) + lo;                      \
            const char* s0 = src + (c) * 16384 + lo;                           \
            gload16(s0,        d0);                                            \
            gload16(s0 + 1024, d0 + 1024);                                     \
            gload16(s0 + 2048, d0 + 2048);                                     \
            gload16(s0 + 3072, d0 + 3072);                                     \
        } while (0)
        STG(0, 0);
        __syncthreads();
#pragma unroll 1
        for (int c = 0; c < 8; ++c) {
            if (c + 1 < 8) STG((c + 1) & 1, c + 1);            // async prefetch
            const char* cb = (const char*)(smem4 + (c & 1) * 1024) + lo;
            float s = 0.f;
#pragma unroll
            for (int j = 0; j < 4; ++j) {
                f32x4 v = *(const f32x4*)(cb + j * 1024);
                s += v.x + v.y + v.z + v.w;
            }
#pragma unroll
            for (int m = 32; m; m >>= 1) s += __shfl_xor(s, m, 64);
            if (lane == 0) ws[D_OFF + row0 + c * 4 + w] = s;   // wave owns the row
            __syncthreads();                                   // chunk c+1 resident
        }
#undef STG
    } else {
        // BN stats: block covers 256 rows (4096 float4), fully coalesced.
        const int bb = blockIdx.x - 1024;                      // 0..127
        const float4* Hv = (const float4*)H + bb * 4096;
        float s0 = 0.f, s1 = 0.f, s2 = 0.f, s3 = 0.f;
        float q0 = 0.f, q1 = 0.f, q2 = 0.f, q3 = 0.f;
#pragma unroll 4
        for (int s = 0; s < 16; ++s) {
            float4 v = Hv[s * 256 + t];
            s0 += v.x; q0 += v.x * v.x;
            s1 += v.y; q1 += v.y * v.y;
            s2 += v.z; q2 += v.z * v.z;
            s3 += v.w; q3 += v.w * v.w;
        }
        float* part = (float*)smem4;                           // [256][8]
        part[t * 8 + 0] = s0; part[t * 8 + 1] = s1;
        part[t * 8 + 2] = s2; part[t * 8 + 3] = s3;
        part[t * 8 + 4] = q0; part[t * 8 + 5] = q1;
        part[t * 8 + 6] = q2; part[t * 8 + 7] = q3;
        __syncthreads();
        if (t < 64) {
            const int g = t >> 2, e = t & 3;   // contributors: threads g+16k
            float a = 0.f, a2 = 0.f;
#pragma unroll
            for (int k = 0; k < 16; ++k) {
                a  += part[(g + 16 * k) * 8 + e];
                a2 += part[(g + 16 * k) * 8 + 4 + e];
            }
            ws[PART_OFF + bb * 64 + t] = a;
            ws[PART_OFF + 128 * 64 + bb * 64 + t] = a2;
        }
    }
}

// ---- Kernel 2: X = Hn@W + b -> d_out;  Yt tiles = bf16(rsqrt(d)*X) swizzled --
// BN finalize folded in: every block redundantly reduces the partials (64KB L2).
__global__ __launch_bounds__(256) void linear_xy(
    const float* __restrict__ H, const float* __restrict__ Wm,
    const float* __restrict__ bias, const float* __restrict__ gamma,
    const float* __restrict__ beta, const float* __restrict__ ws,
    float* __restrict__ X, unsigned short* __restrict__ Yt) {
    __shared__ float Wl[NC * NO];
    __shared__ float hnbuf[4][NC];
    __shared__ unsigned short ytile[64][66];
    __shared__ float ls[256], ls2[256];
    __shared__ float sscale[64], sshift[64];
    const int b = blockIdx.x >> 4, ch = blockIdx.x & 15;   // ch = K-tile index
    const int r0g = b * NL + ch * 64;
    const int t = threadIdx.x, lane = t & 63, w = t >> 6;
    // --- inline BN finalize (redundant per block) ---
    {
        const float* ps  = ws + PART_OFF;
        const float* ps2 = ws + PART_OFF + 128 * 64;
        const int c = t & 63, q = t >> 6;
        float s = 0.f, s2 = 0.f;
        for (int p = q * 32; p < q * 32 + 32; ++p) {
            s  += ps[p * 64 + c];
            s2 += ps2[p * 64 + c];
        }
        ls[t] = s; ls2[t] = s2;
        __syncthreads();
        if (t < 64) {
            float T  = ls[c]  + ls[c + 64]  + ls[c + 128]  + ls[c + 192];
            float T2 = ls2[c] + ls2[c + 64] + ls2[c + 128] + ls2[c + 192];
            const float n = (float)(NB * NL);
            float mean = T / n;
            float var  = T2 / n - mean * mean;
            float sc = gamma[c] * rsqrtf(var + BN_EPS);
            sscale[c] = sc;
            sshift[c] = beta[c] - mean * sc;
        }
    }
    for (int k = t; k < NC * NO; k += 256) Wl[k] = Wm[k];
    __syncthreads();
    const float sc = sscale[lane];
    const float sh = sshift[lane];
    const float bo = bias[lane];
    const float* dbuf = ws + D_OFF;
    for (int rr = w; rr < 64; rr += 4) {
        const int row = r0g + rr;
        float h = H[(size_t)row * NC + lane];
        hnbuf[w][lane] = h * sc + sh;
        float x = bo;
#pragma unroll
        for (int c4 = 0; c4 < NC; c4 += 4) {
            float4 h4 = *(const float4*)(&hnbuf[w][c4]);
            x += h4.x * Wl[(c4 + 0) * NO + lane];
            x += h4.y * Wl[(c4 + 1) * NO + lane];
            x += h4.z * Wl[(c4 + 2) * NO + lane];
            x += h4.w * Wl[(c4 + 3) * NO + lane];
        }
        X[(size_t)row * NO + lane] = x;
        ytile[rr][lane] = f2bf(x * rsqrtf(dbuf[row]));
    }
    __syncthreads();
    // tiled swizzled write: tile (b,ch), element (col, kk=lane)
    char* ybase = (char*)Yt + (size_t)(b * 16 + ch) * 8192;
#pragma unroll
    for (int i2 = 0; i2 < 16; ++i2) {
        const int col = i2 * 4 + w;
        *(unsigned short*)(ybase + ((col * 128 + lane * 2) ^ ((col & 7) << 4))) =
            ytile[lane][col];
    }
}

// ---- Kernel 3: out = leaky(X - sqrt(d_i) * (A @ Y))  [MFMA, fp32 A staging] --
// 64-row tiles, 512 blocks = 2 blocks/CU. A staged fp32 via gload_lds with
// source-side XOR swizzle (rule 21); fragment converted in-register via
// v_cvt_pk_bf16_f32. No bf16 A copy in memory at all.
__global__ __launch_bounds__(256) void prop_mfma(
    const float* __restrict__ A, const unsigned short* __restrict__ Yt,
    const float* __restrict__ dbuf, float* __restrict__ XO) {

    __shared__ float Abuf[2][64 * 64];             // 2 x 16 KB fp32 (swizzled)
    __shared__ unsigned short Ybuf[2][64 * 64];    // 2 x 8 KB bf16 (pre-swizzled)
    __shared__ float sdl[64];

    const int b  = blockIdx.x >> 4;
    const int mt = blockIdx.x & 15;
    const int i0 = mt * 64;
    const char* Abase = (const char*)A + ((size_t)(b * NL + i0)) * 4096;
    const char* YbT   = (const char*)Yt + (size_t)b * 16 * 8192;

    const int t    = threadIdx.x;
    const int lane = t & 63;
    const int w    = t >> 6;

    if (t < 64) sdl[t] = sqrtf(dbuf[b * NL + i0 + t]);

    // A staging: 4 gload16/thread. dest L = i*4096 + t*16 (linear);
    // src = row-major A + inverse XOR on the 16B granule within the 256B row.
    const int tr = t >> 4;               // 0..15
    const int tc = (t & 15) * 16;        // byte col 0..240
    const char* As[4];
#pragma unroll
    for (int i = 0; i < 4; ++i) {
        const int row = i * 16 + tr;     // 0..63
        As[i] = Abase + (size_t)row * 4096 + (tc ^ ((row & 7) << 4));
    }
    const int yL0 = t * 16, yL1 = t * 16 + 4096;

    const int wr0  = (w >> 1) * 32;
    const int wc0  = (w & 1) * 32;
    const int frow = wr0 + (lane & 31);
    const int fcol = wc0 + (lane & 31);
    const int khb  = (lane >> 5) * 16;   // bf16 half-offset in 128B row
    const int kfh  = (lane >> 5) * 32;   // fp32 half-offset in 256B row
    const int swA  = (frow & 7) << 4;
    const int swY  = (fcol & 7) << 4;

    f32x16 acc;
#pragma unroll
    for (int r = 0; r < 16; ++r) acc[r] = 0.f;

#define STAGE(bi, kt) do {                                                     \
        char* ad = (char*)Abuf[bi];                                            \
        gload16(As[0] + (kt) * 256, ad + t * 16);                              \
        gload16(As[1] + (kt) * 256, ad + 4096  + t * 16);                      \
        gload16(As[2] + (kt) * 256, ad + 8192  + t * 16);                      \
        gload16(As[3] + (kt) * 256, ad + 12288 + t * 16);                      \
        const char* ys = YbT + (size_t)(kt) * 8192;                            \
        char* yd = (char*)Ybuf[bi];                                            \
        gload16(ys + yL0, yd + yL0);                                           \
        gload16(ys + yL1, yd + yL1);                                           \
    } while (0)

    STAGE(0, 0);
    __syncthreads();

#pragma unroll 1
    for (int kti = 0; kti < 16; ++kti) {
        const int nxt = kti + 1;
        if (nxt < 16) STAGE(nxt & 1, nxt);      // prefetch next tile (async)
        const char* ab  = (const char*)Abuf[kti & 1];
        const char* yb2 = (const char*)Ybuf[kti & 1];
#pragma unroll
        for (int ks = 0; ks < 4; ++ks) {
            const int b0 = frow * 256 + ks * 64 + kfh;
            f32x4 flo = *(const f32x4*)(ab + ((b0)      ^ swA));
            f32x4 fhi = *(const f32x4*)(ab + ((b0 + 16) ^ swA));
            s16x8 af = cvt8(flo, fhi);
            s16x8 bf = *(const s16x8*)(yb2 + ((fcol * 128 + ks * 32 + khb) ^ swY));
            acc = __builtin_amdgcn_mfma_f32_32x32x16_bf16(af, bf, acc, 0, 0, 0);
        }
        __syncthreads();                        // drains vmcnt: next tile resident
    }
#undef STAGE

    // epilogue: out = leaky(X - sqrt(d_i) * acc)
#pragma unroll
    for (int reg = 0; reg < 16; ++reg) {
        int row = (reg & 3) + 8 * (reg >> 2) + 4 * (lane >> 5);
        int i   = i0 + wr0 + row;
        int col = wc0 + (lane & 31);
        size_t idx = ((size_t)(b * NL + i)) * NO + col;
        float x = XO[idx];
        float v = x - sdl[wr0 + row] * acc[reg];
        XO[idx] = v > 0.f ? v : 0.01f * v;
    }
}

extern "C" void kernel_launch(void* const* d_in, const int* in_sizes, int n_in,
                              void* d_out, int out_size, void* d_ws, size_t ws_size,
                              hipStream_t stream) {
    const float* H     = (const float*)d_in[0];
    const float* A     = (const float*)d_in[1];
    const float* gamma = (const float*)d_in[2];
    const float* beta  = (const float*)d_in[3];
    const float* Wm    = (const float*)d_in[4];
    const float* bias  = (const float*)d_in[5];
    float* out = (float*)d_out;
    float* ws  = (float*)d_ws;
    unsigned short* Yt = (unsigned short*)(ws + YT_OFF);

    deg_bn<<<1152, 256, 0, stream>>>(A, H, ws);
    linear_xy<<<512, 256, 0, stream>>>(H, Wm, bias, gamma, beta, ws, out, Yt);
    prop_mfma<<<512, 256, 0, stream>>>(A, Yt, ws + D_OFF, out);
}